// Round 2
// baseline (465.568 us; speedup 1.0000x reference)
//
#include <hip/hip_runtime.h>
#include <stdint.h>

// E=8, T=4096, H=1024, I=512. fp32 I/O, bf16 MFMA compute internally.
// d_ws layout (128 MiB): w1b | w2b | w3b | w4b | h1(=h3) | h2(=xb)  (all bf16)
// xb (bf16 copy of x) aliases h2: dead before GEMM2 writes h2.

#define BM 256
#define BN 256
#define BK 64

typedef __attribute__((ext_vector_type(8))) short short8;
typedef __attribute__((ext_vector_type(4))) float float4v;
typedef __attribute__((ext_vector_type(4))) uint16_t ushort4v;

__device__ __forceinline__ uint16_t f32_to_bf16_rne(float f) {
    union { float f; uint32_t u; } v; v.f = f;
    uint32_t u = v.u;
    return (uint16_t)((u + 0x7FFFu + ((u >> 16) & 1u)) >> 16);
}

// prep: blocks [0,4096): transpose+convert the 4 weights in 64x64 tiles,
//       [E][R][C] f32 -> [E][C][R] bf16, float4 loads / ushort4 stores.
//       blocks [4096,12288): fp32->bf16 convert of x, 16 elems/thread.
__global__ __launch_bounds__(256) void prep_all(
    const float* __restrict__ x,
    const float* __restrict__ i0, const float* __restrict__ i1,
    const float* __restrict__ i2, const float* __restrict__ i3,
    uint16_t* __restrict__ xb,
    uint16_t* __restrict__ o0, uint16_t* __restrict__ o1,
    uint16_t* __restrict__ o2, uint16_t* __restrict__ o3) {
    int bx = blockIdx.x;
    int tid = threadIdx.x;
    if (bx >= 4096) {
        // x convert: 8192 blocks * 256 threads * 16 = 33,554,432 = E*T*H exactly
        size_t idx = ((size_t)(bx - 4096) * 256 + tid) * 16;
        float4 v0 = *(const float4*)(x + idx);
        float4 v1 = *(const float4*)(x + idx + 4);
        float4 v2 = *(const float4*)(x + idx + 8);
        float4 v3 = *(const float4*)(x + idx + 12);
        short8 s0, s1;
        s0[0] = (short)f32_to_bf16_rne(v0.x); s0[1] = (short)f32_to_bf16_rne(v0.y);
        s0[2] = (short)f32_to_bf16_rne(v0.z); s0[3] = (short)f32_to_bf16_rne(v0.w);
        s0[4] = (short)f32_to_bf16_rne(v1.x); s0[5] = (short)f32_to_bf16_rne(v1.y);
        s0[6] = (short)f32_to_bf16_rne(v1.z); s0[7] = (short)f32_to_bf16_rne(v1.w);
        s1[0] = (short)f32_to_bf16_rne(v2.x); s1[1] = (short)f32_to_bf16_rne(v2.y);
        s1[2] = (short)f32_to_bf16_rne(v2.z); s1[3] = (short)f32_to_bf16_rne(v2.w);
        s1[4] = (short)f32_to_bf16_rne(v3.x); s1[5] = (short)f32_to_bf16_rne(v3.y);
        s1[6] = (short)f32_to_bf16_rne(v3.z); s1[7] = (short)f32_to_bf16_rne(v3.w);
        *(short8*)(xb + idx) = s0;
        *(short8*)(xb + idx + 8) = s1;
        return;
    }
    __shared__ float tile[64][65];
    int w = bx >> 10;                  // weight 0..3
    int t = bx & 1023;
    int e = t >> 7;                    // expert
    int t2 = t & 127;                  // tile within expert (128 64x64 tiles)
    const float* in = (w == 0) ? i0 : (w == 1) ? i1 : (w == 2) ? i2 : i3;
    uint16_t* out = (w == 0) ? o0 : (w == 1) ? o1 : (w == 2) ? o2 : o3;
    int R = (w & 1) ? 512 : 1024;      // w1,w3 are [H,I]; w2,w4 are [I,H]
    int C = (w & 1) ? 1024 : 512;
    int tilesX = C >> 6;               // 8 or 16
    int cx = t2 & (tilesX - 1);
    int ry = (w & 1) ? (t2 >> 4) : (t2 >> 3);
    int r0 = ry * 64, c0 = cx * 64;
    const float* src = in + (size_t)e * R * C;
    uint16_t* dst = out + (size_t)e * R * C;
    int lc = (tid & 15) * 4;           // col group
    int lr = tid >> 4;                 // 0..15
#pragma unroll
    for (int p = 0; p < 4; ++p) {
        int row = lr + 16 * p;
        float4 v = *(const float4*)(src + (size_t)(r0 + row) * C + (c0 + lc));
        tile[row][lc + 0] = v.x;
        tile[row][lc + 1] = v.y;
        tile[row][lc + 2] = v.z;
        tile[row][lc + 3] = v.w;
    }
    __syncthreads();
#pragma unroll
    for (int p = 0; p < 4; ++p) {
        int cy = lr + 16 * p;          // dst row (= orig col)
        ushort4v u;
        u[0] = f32_to_bf16_rne(tile[lc + 0][cy]);
        u[1] = f32_to_bf16_rne(tile[lc + 1][cy]);
        u[2] = f32_to_bf16_rne(tile[lc + 2][cy]);
        u[3] = f32_to_bf16_rne(tile[lc + 3][cy]);
        *(ushort4v*)(dst + (size_t)(c0 + cy) * R + (r0 + lc)) = u;
    }
}

__device__ __forceinline__ void storeC4(float* p, float4 v) {
    *(float4*)p = v;
}
__device__ __forceinline__ void storeC4(uint16_t* p, float4 v) {
    ushort4v u;
    u[0] = f32_to_bf16_rne(v.x); u[1] = f32_to_bf16_rne(v.y);
    u[2] = f32_to_bf16_rne(v.z); u[3] = f32_to_bf16_rne(v.w);
    *(ushort4v*)p = u;
}

// C[e][M][N] = A[e][M][K] * B[e][N][K]^T, A and B bf16 K-contiguous.
// 256x256 tile, BK=64, 8 waves (2M x 4N), each wave 128x64 = 8x4 MFMA 16x16x32 tiles.
// Same proven 2-phase ping-pong sync structure as the 128^2 version: stage tile t+1
// via global_load_lds before computing tile t, single barrier per K-step.
// LDS slot swizzle kb' = kb ^ (row&7) keeps fragment ds_read_b128 conflict-free.
// Epilogue bounces acc through LDS (per-wave private region) for dwordx4/x2 C stores.
// 1D grid, XCD-chunked bijective swizzle: each XCD owns 1-2 experts' contiguous tiles.
template <typename OutT>
__global__ __launch_bounds__(512, 2) void gemm_tn(
    const uint16_t* __restrict__ A,
    const uint16_t* __restrict__ B,
    OutT* __restrict__ C,
    int M, int N, int K)
{
    __shared__ __align__(16) uint16_t As[2][BM * BK];   // 2 x 32 KiB
    __shared__ __align__(16) uint16_t Bs[2][BN * BK];   // 2 x 32 KiB

    const int tid  = threadIdx.x;
    const int lane = tid & 63;
    const int wave = tid >> 6;          // 0..7
    const int wr = wave >> 2, wc = wave & 3;   // 2 x 4 wave grid
    const int frow = lane & 15;
    const int quad = lane >> 4;
    const int xm = frow & 7;            // fragment-read xor mask

    // decode swizzled 1D block id (gridDim.x divisible by 8)
    const int gxs = (N == 512) ? 1 : 2; // gx = N/BN is 2 or 4
    int id = blockIdx.x;
    int chunk = gridDim.x >> 3;
    int id2 = (id & 7) * chunk + (id >> 3);
    int bxi = id2 & ((1 << gxs) - 1);
    int rest = id2 >> gxs;
    int byi = rest & 15;                // gy = M/BM = 4096/256 = 16
    int e   = rest >> 4;
    const int bm = byi * BM;
    const int bn = bxi * BN;

    // staging map: thread t covers LDS 16B slot (row = t>>3 + 64*i, slot = t&7);
    // global source block kb = (t&7) ^ (row&7); LDS addr = t*16 (linear, lane x 16)
    const int srow = tid >> 3;                     // 0..63
    const int skb  = (tid & 7) ^ (srow & 7);
    const uint16_t* Ag = A + (size_t)e * M * K + (size_t)(bm + srow) * K + skb * 8;
    const uint16_t* Bg = B + (size_t)e * N * K + (size_t)(bn + srow) * K + skb * 8;

    float4v acc[8][4];
#pragma unroll
    for (int i = 0; i < 8; ++i)
#pragma unroll
        for (int j = 0; j < 4; ++j)
            acc[i][j] = (float4v){0.f, 0.f, 0.f, 0.f};

    char* AsB = (char*)As;
    char* BsB = (char*)Bs;
    const int ldsoff = wave * 1024;

    auto stage = [&](int buf, int k0) {
        char* asb = AsB + buf * (BM * BK * 2);
        char* bsb = BsB + buf * (BN * BK * 2);
#pragma unroll
        for (int i = 0; i < 4; ++i) {
            __builtin_amdgcn_global_load_lds(
                (const __attribute__((address_space(1))) void*)(Ag + k0 + (size_t)i * 64 * K),
                (__attribute__((address_space(3))) void*)(asb + i * 8192 + ldsoff),
                16, 0, 0);
            __builtin_amdgcn_global_load_lds(
                (const __attribute__((address_space(1))) void*)(Bg + k0 + (size_t)i * 64 * K),
                (__attribute__((address_space(3))) void*)(bsb + i * 8192 + ldsoff),
                16, 0, 0);
        }
    };

    stage(0, 0);                         // prologue: tile 0 -> buf 0
    const int nk = K / BK;
    int cur = 0;
    for (int t = 0; t < nk; ++t) {
        // barrier (implicit vmcnt(0) drain): buf[cur] staged & readers of buf[cur^1] done
        __syncthreads();
        if (t + 1 < nk) stage(cur ^ 1, (t + 1) * BK);   // prefetch overlaps compute below
        const char* asb = AsB + cur * (BM * BK * 2);
        const char* bsb = BsB + cur * (BN * BK * 2);
#pragma unroll
        for (int s = 0; s < 2; ++s) {
            short8 a[8], b[4];
            const int kb = ((s * 4 + quad) ^ xm) * 16;  // swizzled byte slot
#pragma unroll
            for (int f = 0; f < 8; ++f)
                a[f] = *(const short8*)(asb + (wr * 128 + f * 16 + frow) * 128 + kb);
#pragma unroll
            for (int f = 0; f < 4; ++f)
                b[f] = *(const short8*)(bsb + (wc * 64 + f * 16 + frow) * 128 + kb);
#pragma unroll
            for (int i = 0; i < 8; ++i)
#pragma unroll
                for (int j = 0; j < 4; ++j)
                    acc[i][j] = __builtin_amdgcn_mfma_f32_16x16x32_bf16(a[i], b[j], acc[i][j], 0, 0, 0);
        }
        cur ^= 1;
    }

    // ---- epilogue: LDS bounce (per-wave private 16x64 f32 region, row stride 68)
    __syncthreads();                    // all waves done reading LDS tiles
    float* bounce = (float*)((char*)As + wave * 4352);   // 16*68*4 = 4352 B per wave
    OutT* Ce = C + (size_t)e * M * N;
    const int colbase = bn + wc * 64;
#pragma unroll
    for (int f = 0; f < 8; ++f) {
#pragma unroll
        for (int j = 0; j < 4; ++j)
#pragma unroll
            for (int r = 0; r < 4; ++r)
                bounce[(quad * 4 + r) * 68 + j * 16 + frow] = acc[f][j][r];
        // same-wave RAW/WAR through LDS: compiler inserts lgkmcnt waits (same pointer)
        int row0 = bm + wr * 128 + f * 16;
#pragma unroll
        for (int p = 0; p < 4; ++p) {
            int lrow = p * 4 + (lane >> 4);
            int lcol = (lane & 15) * 4;
            float4 v = *(const float4*)(bounce + lrow * 68 + lcol);
            storeC4(&Ce[(size_t)(row0 + lrow) * N + colbase + lcol], v);
        }
    }
}

extern "C" void kernel_launch(void* const* d_in, const int* in_sizes, int n_in,
                              void* d_out, int out_size, void* d_ws, size_t ws_size,
                              hipStream_t stream) {
    const float* x  = (const float*)d_in[0];
    const float* w1 = (const float*)d_in[1];
    const float* w2 = (const float*)d_in[2];
    const float* w3 = (const float*)d_in[3];
    const float* w4 = (const float*)d_in[4];
    float* out = (float*)d_out;

    const int E = 8, T = 4096, H = 1024, I = 512;

    char* p = (char*)d_ws;
    uint16_t* w1b = (uint16_t*)p; p += (size_t)E * H * I * 2;   // 8 MiB, [E][I][H]
    uint16_t* w2b = (uint16_t*)p; p += (size_t)E * H * I * 2;   //        [E][H][I]
    uint16_t* w3b = (uint16_t*)p; p += (size_t)E * H * I * 2;
    uint16_t* w4b = (uint16_t*)p; p += (size_t)E * H * I * 2;
    uint16_t* h1  = (uint16_t*)p; p += (size_t)E * T * I * 2;   // 32 MiB
    uint16_t* h2  = (uint16_t*)p; p += (size_t)E * T * H * 2;   // 64 MiB
    uint16_t* h3  = h1;  // h1 dead once gemm3 runs
    uint16_t* xb  = h2;  // bf16 x aliases h2: dead before gemm2 writes h2

    // prep: 4096 weight-transpose tiles (64x64) + 8192 x-convert blocks, one launch
    prep_all<<<dim3(4096 + 8192), dim3(256), 0, stream>>>(
        x, w1, w2, w3, w4, xb, w1b, w2b, w3b, w4b);

    // h1 = x @ w1          [T,H]x[H,I] -> [T,I]   256 blocks (1 expert / XCD)
    gemm_tn<uint16_t><<<dim3((I / BN) * (T / BM) * E), dim3(512), 0, stream>>>(xb, w1b, h1, T, I, H);
    // h2 = h1 @ w2         [T,I]x[I,H] -> [T,H]   512 blocks (2 experts / XCD)
    gemm_tn<uint16_t><<<dim3((H / BN) * (T / BM) * E), dim3(512), 0, stream>>>(h1, w2b, h2, T, H, I);
    // h3 = h2 @ w3         [T,H]x[H,I] -> [T,I]
    gemm_tn<uint16_t><<<dim3((I / BN) * (T / BM) * E), dim3(512), 0, stream>>>(h2, w3b, h3, T, I, H);
    // out = h3 @ w4        [T,I]x[I,H] -> [T,H], fp32 out
    gemm_tn<float><<<dim3((H / BN) * (T / BM) * E), dim3(512), 0, stream>>>(h3, w4b, out, T, H, I);
}

// Round 4
// 463.793 us; speedup vs baseline: 1.0038x; 1.0038x over previous
//
#include <hip/hip_runtime.h>
#include <stdint.h>

// E=8, T=4096, H=1024, I=512. fp32 I/O, bf16 MFMA compute internally.
// d_ws layout (128 MiB): w1b | w2b | w3b | w4b | h1(=h3) | h2(=xb)  (all bf16)
// xb (bf16 copy of x) aliases h2: dead before GEMM2 writes h2.
// (Round-4 resubmit of round-3 kernel: bench infra failed; no kernel-side
//  hang/fault mechanism found on audit — barriers are uniform, vmcnt counts
//  only the 8 stage loads, addresses in-bounds, 128 KiB LDS ran in round 2.)

#define BM 256
#define BN 256
#define BK 64

typedef __attribute__((ext_vector_type(8))) short short8;
typedef __attribute__((ext_vector_type(4))) float float4v;
typedef __attribute__((ext_vector_type(4))) uint16_t ushort4v;

__device__ __forceinline__ uint16_t f32_to_bf16_rne(float f) {
    union { float f; uint32_t u; } v; v.f = f;
    uint32_t u = v.u;
    return (uint16_t)((u + 0x7FFFu + ((u >> 16) & 1u)) >> 16);
}

// prep: blocks [0,16384): transpose+convert the 4 weights, 32x32 tiles (conflict-free
//       [32][33] LDS pattern — round-1 measured layout). [E][R][C] f32 -> [E][C][R] bf16.
//       blocks [16384,24576): fp32->bf16 convert of x, 16 elems/thread.
__global__ __launch_bounds__(256) void prep_all(
    const float* __restrict__ x,
    const float* __restrict__ i0, const float* __restrict__ i1,
    const float* __restrict__ i2, const float* __restrict__ i3,
    uint16_t* __restrict__ xb,
    uint16_t* __restrict__ o0, uint16_t* __restrict__ o1,
    uint16_t* __restrict__ o2, uint16_t* __restrict__ o3) {
    __shared__ float tile[32][33];
    int bx = blockIdx.x;
    int tid = threadIdx.x;
    if (bx >= 16384) {
        // x convert: 8192 blocks * 256 threads * 16 = 33,554,432 = E*T*H exactly
        size_t idx = ((size_t)(bx - 16384) * 256 + tid) * 16;
        float4 v0 = *(const float4*)(x + idx);
        float4 v1 = *(const float4*)(x + idx + 4);
        float4 v2 = *(const float4*)(x + idx + 8);
        float4 v3 = *(const float4*)(x + idx + 12);
        short8 s0, s1;
        s0[0] = (short)f32_to_bf16_rne(v0.x); s0[1] = (short)f32_to_bf16_rne(v0.y);
        s0[2] = (short)f32_to_bf16_rne(v0.z); s0[3] = (short)f32_to_bf16_rne(v0.w);
        s0[4] = (short)f32_to_bf16_rne(v1.x); s0[5] = (short)f32_to_bf16_rne(v1.y);
        s0[6] = (short)f32_to_bf16_rne(v1.z); s0[7] = (short)f32_to_bf16_rne(v1.w);
        s1[0] = (short)f32_to_bf16_rne(v2.x); s1[1] = (short)f32_to_bf16_rne(v2.y);
        s1[2] = (short)f32_to_bf16_rne(v2.z); s1[3] = (short)f32_to_bf16_rne(v2.w);
        s1[4] = (short)f32_to_bf16_rne(v3.x); s1[5] = (short)f32_to_bf16_rne(v3.y);
        s1[6] = (short)f32_to_bf16_rne(v3.z); s1[7] = (short)f32_to_bf16_rne(v3.w);
        *(short8*)(xb + idx) = s0;
        *(short8*)(xb + idx + 8) = s1;
        return;
    }
    int w = bx >> 12;
    int t = bx & 4095;
    int e = t >> 9;
    int t2 = t & 511;
    const float* in = (w == 0) ? i0 : (w == 1) ? i1 : (w == 2) ? i2 : i3;
    uint16_t* out = (w == 0) ? o0 : (w == 1) ? o1 : (w == 2) ? o2 : o3;
    int R = (w & 1) ? 512 : 1024;      // w1,w3 are [H,I]; w2,w4 are [I,H]
    int C = (w & 1) ? 1024 : 512;
    int tilesX = C >> 5;               // 16 or 32
    int cx = t2 & (tilesX - 1);
    int ry = t2 / tilesX;
    int r0 = ry * 32, c0 = cx * 32;
    const float* src = in + (size_t)e * R * C;
    uint16_t* dst = out + (size_t)e * R * C;
    int tx = tid & 31;
    int ty = tid >> 5;  // 0..7
#pragma unroll
    for (int j = 0; j < 32; j += 8)
        tile[ty + j][tx] = src[(size_t)(r0 + ty + j) * C + (c0 + tx)];
    __syncthreads();
#pragma unroll
    for (int j = 0; j < 32; j += 8)
        dst[(size_t)(c0 + ty + j) * R + (r0 + tx)] = f32_to_bf16_rne(tile[tx][ty + j]);
}

__device__ __forceinline__ void storeC4(float* p, float4 v) {
    *(float4*)p = v;
}
__device__ __forceinline__ void storeC4(uint16_t* p, float4 v) {
    ushort4v u;
    u[0] = f32_to_bf16_rne(v.x); u[1] = f32_to_bf16_rne(v.y);
    u[2] = f32_to_bf16_rne(v.z); u[3] = f32_to_bf16_rne(v.w);
    *(ushort4v*)p = u;
}

// C[e][M][N] = A[e][M][K] * B[e][N][K]^T, A and B bf16 K-contiguous.
// 256x256 tile, BK=64, 8 waves (2M x 4N), each wave 128x64 = 8x4 MFMA 16x16x32 tiles.
// Counted-vmcnt ping-pong (T4): raw s_barriers, NEVER vmcnt(0) in the main loop.
//   barrier(a); stage(next) [8 loads/wave -> 16 outstanding]; vmcnt(8) [old 8 only];
//   barrier(b); compute.   New loads land under the whole compute phase.
// LDS slot swizzle kb' = kb ^ (row&7) keeps fragment ds_read_b128 conflict-free.
// Epilogue bounces acc through LDS for dwordx4/x2 coalesced C stores.
// 1D grid, XCD-chunked bijective swizzle: each XCD owns 1-2 experts' contiguous tiles.
template <typename OutT>
__global__ __launch_bounds__(512, 2) void gemm_tn(
    const uint16_t* __restrict__ A,
    const uint16_t* __restrict__ B,
    OutT* __restrict__ C,
    int M, int N, int K)
{
    __shared__ __align__(16) uint16_t As[2][BM * BK];   // 2 x 32 KiB
    __shared__ __align__(16) uint16_t Bs[2][BN * BK];   // 2 x 32 KiB

    const int tid  = threadIdx.x;
    const int lane = tid & 63;
    const int wave = tid >> 6;          // 0..7
    const int wr = wave >> 2, wc = wave & 3;   // 2 x 4 wave grid
    const int frow = lane & 15;
    const int quad = lane >> 4;
    const int xm = frow & 7;            // fragment-read xor mask

    // decode swizzled 1D block id (gridDim.x divisible by 8)
    const int gxs = (N == 512) ? 1 : 2; // gx = N/BN is 2 or 4
    int id = blockIdx.x;
    int chunk = gridDim.x >> 3;
    int id2 = (id & 7) * chunk + (id >> 3);
    int bxi = id2 & ((1 << gxs) - 1);
    int rest = id2 >> gxs;
    int byi = rest & 15;                // gy = M/BM = 4096/256 = 16
    int e   = rest >> 4;
    const int bm = byi * BM;
    const int bn = bxi * BN;

    // staging map: thread t covers LDS 16B slot (row = t>>3 + 64*i, slot = t&7);
    // global source block kb = (t&7) ^ (row&7); LDS addr = t*16 (linear, lane x 16)
    const int srow = tid >> 3;                     // 0..63
    const int skb  = (tid & 7) ^ (srow & 7);
    const uint16_t* Ag = A + (size_t)e * M * K + (size_t)(bm + srow) * K + skb * 8;
    const uint16_t* Bg = B + (size_t)e * N * K + (size_t)(bn + srow) * K + skb * 8;

    float4v acc[8][4];
#pragma unroll
    for (int i = 0; i < 8; ++i)
#pragma unroll
        for (int j = 0; j < 4; ++j)
            acc[i][j] = (float4v){0.f, 0.f, 0.f, 0.f};

    char* AsB = (char*)As;
    char* BsB = (char*)Bs;
    const int ldsoff = wave * 1024;

    auto stage = [&](int buf, int k0) {
        char* asb = AsB + buf * (BM * BK * 2);
        char* bsb = BsB + buf * (BN * BK * 2);
#pragma unroll
        for (int i = 0; i < 4; ++i) {
            __builtin_amdgcn_global_load_lds(
                (const __attribute__((address_space(1))) void*)(Ag + k0 + (size_t)i * 64 * K),
                (__attribute__((address_space(3))) void*)(asb + i * 8192 + ldsoff),
                16, 0, 0);
            __builtin_amdgcn_global_load_lds(
                (const __attribute__((address_space(1))) void*)(Bg + k0 + (size_t)i * 64 * K),
                (__attribute__((address_space(3))) void*)(bsb + i * 8192 + ldsoff),
                16, 0, 0);
        }
    };

    auto compute = [&](int buf) {
        const char* asb = AsB + buf * (BM * BK * 2);
        const char* bsb = BsB + buf * (BN * BK * 2);
#pragma unroll
        for (int s = 0; s < 2; ++s) {
            short8 a[8], b[4];
            const int kb = ((s * 4 + quad) ^ xm) * 16;  // swizzled byte slot
#pragma unroll
            for (int f = 0; f < 8; ++f)
                a[f] = *(const short8*)(asb + (wr * 128 + f * 16 + frow) * 128 + kb);
#pragma unroll
            for (int f = 0; f < 4; ++f)
                b[f] = *(const short8*)(bsb + (wc * 64 + f * 16 + frow) * 128 + kb);
#pragma unroll
            for (int i = 0; i < 8; ++i)
#pragma unroll
                for (int j = 0; j < 4; ++j)
                    acc[i][j] = __builtin_amdgcn_mfma_f32_16x16x32_bf16(a[i], b[j], acc[i][j], 0, 0, 0);
        }
    };

    stage(0, 0);                         // prologue: tile 0 -> buf 0 (8 loads in flight)
    const int nk = K / BK;
    int cur = 0;
    for (int t = 0; t + 1 < nk; ++t) {
        __builtin_amdgcn_s_barrier();    // (a) all waves done reading buf[cur^1]; no drain
        __builtin_amdgcn_sched_barrier(0);
        stage(cur ^ 1, (t + 1) * BK);    // -> 16 outstanding/wave
        asm volatile("s_waitcnt vmcnt(8)" ::: "memory");   // old 8 (buf[cur]) landed
        __builtin_amdgcn_s_barrier();    // (b) cross-wave: everyone's buf[cur] landed
        __builtin_amdgcn_sched_barrier(0);
        compute(cur);                    // new 8 loads fly under this whole phase
        cur ^= 1;
    }
    // tail: last staged buffer, no further prefetch
    asm volatile("s_waitcnt vmcnt(0)" ::: "memory");
    __builtin_amdgcn_s_barrier();
    __builtin_amdgcn_sched_barrier(0);
    compute(cur);

    // ---- epilogue: LDS bounce (per-wave private 16x64 f32 region, row stride 68)
    __syncthreads();                    // full drain OK here (once)
    float* bounce = (float*)((char*)As + wave * 4352);   // 16*68*4 = 4352 B per wave
    OutT* Ce = C + (size_t)e * M * N;
    const int colbase = bn + wc * 64;
#pragma unroll
    for (int f = 0; f < 8; ++f) {
#pragma unroll
        for (int j = 0; j < 4; ++j)
#pragma unroll
            for (int r = 0; r < 4; ++r)
                bounce[(quad * 4 + r) * 68 + j * 16 + frow] = acc[f][j][r];
        // same-wave RAW through LDS: compiler inserts lgkmcnt waits
        int row0 = bm + wr * 128 + f * 16;
#pragma unroll
        for (int p = 0; p < 4; ++p) {
            int lrow = p * 4 + (lane >> 4);
            int lcol = (lane & 15) * 4;
            float4 v = *(const float4*)(bounce + lrow * 68 + lcol);
            storeC4(&Ce[(size_t)(row0 + lrow) * N + colbase + lcol], v);
        }
    }
}

extern "C" void kernel_launch(void* const* d_in, const int* in_sizes, int n_in,
                              void* d_out, int out_size, void* d_ws, size_t ws_size,
                              hipStream_t stream) {
    const float* x  = (const float*)d_in[0];
    const float* w1 = (const float*)d_in[1];
    const float* w2 = (const float*)d_in[2];
    const float* w3 = (const float*)d_in[3];
    const float* w4 = (const float*)d_in[4];
    float* out = (float*)d_out;

    const int E = 8, T = 4096, H = 1024, I = 512;

    char* p = (char*)d_ws;
    uint16_t* w1b = (uint16_t*)p; p += (size_t)E * H * I * 2;   // 8 MiB, [E][I][H]
    uint16_t* w2b = (uint16_t*)p; p += (size_t)E * H * I * 2;   //        [E][H][I]
    uint16_t* w3b = (uint16_t*)p; p += (size_t)E * H * I * 2;
    uint16_t* w4b = (uint16_t*)p; p += (size_t)E * H * I * 2;
    uint16_t* h1  = (uint16_t*)p; p += (size_t)E * T * I * 2;   // 32 MiB
    uint16_t* h2  = (uint16_t*)p; p += (size_t)E * T * H * 2;   // 64 MiB
    uint16_t* h3  = h1;  // h1 dead once gemm3 runs
    uint16_t* xb  = h2;  // bf16 x aliases h2: dead before gemm2 writes h2

    // prep: 16384 weight-transpose tiles (32x32) + 8192 x-convert blocks, one launch
    prep_all<<<dim3(16384 + 8192), dim3(256), 0, stream>>>(
        x, w1, w2, w3, w4, xb, w1b, w2b, w3b, w4b);

    // h1 = x @ w1          [T,H]x[H,I] -> [T,I]   256 blocks (1 expert / XCD)
    gemm_tn<uint16_t><<<dim3((I / BN) * (T / BM) * E), dim3(512), 0, stream>>>(xb, w1b, h1, T, I, H);
    // h2 = h1 @ w2         [T,I]x[I,H] -> [T,H]   512 blocks (2 experts / XCD)
    gemm_tn<uint16_t><<<dim3((H / BN) * (T / BM) * E), dim3(512), 0, stream>>>(h1, w2b, h2, T, H, I);
    // h3 = h2 @ w3         [T,H]x[H,I] -> [T,I]
    gemm_tn<uint16_t><<<dim3((I / BN) * (T / BM) * E), dim3(512), 0, stream>>>(h2, w3b, h3, T, I, H);
    // out = h3 @ w4        [T,I]x[I,H] -> [T,H], fp32 out
    gemm_tn<float><<<dim3((H / BN) * (T / BM) * E), dim3(512), 0, stream>>>(h3, w4b, out, T, H, I);
}

// Round 5
// 416.283 us; speedup vs baseline: 1.1184x; 1.1141x over previous
//
#include <hip/hip_runtime.h>
#include <stdint.h>

// E=8, T=4096, H=1024, I=512.
// The reference chain is LINEAR (4 einsums, no activation), so precombine:
//   out[e] = x[e] @ W[e],  W = w1 w2 w3 w4  (per expert).
// Computed transposed so everything is TN (C = A * B^T, B K-contiguous) with only
// w4 needing a physical transpose:
//   Q1[h2,h1] = sum_i  w4b[h2,i] * w3[h1,i]     A=w4^T(bf16)  B=w3(as stored)
//   Q2[h2,i ] = sum_h1 Q1[h2,h1] * w2[i,h1]     A=Q1(fp32)    B=w2(as stored)
//   Wt[h2,h ] = sum_i  Q2[h2,i ] * w1[h,i]      A=Q2(fp32)    B=w1(as stored)
//   out[t,h2] = sum_h  x[t,h]    * Wt[h2,h]     A=x (fp32)    B=Wt
// FLOPs 137.4G -> 94.5G; h1/h2/h3 HBM round-trips eliminated.
// Q1,Q2 fp32 for numerics; weights/Wt bf16.
// d_ws (96 MiB): w1c 8 | w2c 8 | w3c 8 | w4b 8 | Q1 32 | Q2 16 | Wt 16

typedef __attribute__((ext_vector_type(8))) short short8;
typedef __attribute__((ext_vector_type(4))) float float4v;
typedef __attribute__((ext_vector_type(4))) uint16_t ushort4v;

__device__ __forceinline__ uint16_t f32_to_bf16_rne(float f) {
    union { float f; uint32_t u; } v; v.f = f;
    uint32_t u = v.u;
    return (uint16_t)((u + 0x7FFFu + ((u >> 16) & 1u)) >> 16);
}

// prep: blocks [0,3072): elementwise fp32->bf16 of w1,w2,w3 (1024 blocks each,
//       4096 elems/block). blocks [3072,7168): w4 transpose+convert,
//       [E][512][1024] -> w4b [E][1024][512], 32x32 tiles ([32][33] LDS).
__global__ __launch_bounds__(256) void prep(
    const float* __restrict__ w1, const float* __restrict__ w2,
    const float* __restrict__ w3, const float* __restrict__ w4,
    uint16_t* __restrict__ w1c, uint16_t* __restrict__ w2c,
    uint16_t* __restrict__ w3c, uint16_t* __restrict__ w4b) {
    int bx = blockIdx.x;
    int tid = threadIdx.x;
    if (bx < 3072) {
        int wsel = bx >> 10;
        const float* src = (wsel == 0) ? w1 : (wsel == 1) ? w2 : w3;
        uint16_t* dst = (wsel == 0) ? w1c : (wsel == 1) ? w2c : w3c;
        size_t idx = ((size_t)(bx & 1023) * 256 + tid) * 16;
        float4 v0 = *(const float4*)(src + idx);
        float4 v1 = *(const float4*)(src + idx + 4);
        float4 v2 = *(const float4*)(src + idx + 8);
        float4 v3 = *(const float4*)(src + idx + 12);
        short8 s0, s1;
        s0[0] = (short)f32_to_bf16_rne(v0.x); s0[1] = (short)f32_to_bf16_rne(v0.y);
        s0[2] = (short)f32_to_bf16_rne(v0.z); s0[3] = (short)f32_to_bf16_rne(v0.w);
        s0[4] = (short)f32_to_bf16_rne(v1.x); s0[5] = (short)f32_to_bf16_rne(v1.y);
        s0[6] = (short)f32_to_bf16_rne(v1.z); s0[7] = (short)f32_to_bf16_rne(v1.w);
        s1[0] = (short)f32_to_bf16_rne(v2.x); s1[1] = (short)f32_to_bf16_rne(v2.y);
        s1[2] = (short)f32_to_bf16_rne(v2.z); s1[3] = (short)f32_to_bf16_rne(v2.w);
        s1[4] = (short)f32_to_bf16_rne(v3.x); s1[5] = (short)f32_to_bf16_rne(v3.y);
        s1[6] = (short)f32_to_bf16_rne(v3.z); s1[7] = (short)f32_to_bf16_rne(v3.w);
        *(short8*)(dst + idx) = s0;
        *(short8*)(dst + idx + 8) = s1;
        return;
    }
    __shared__ float tile[32][33];
    int t = bx - 3072;                 // 0..4095
    int e = t >> 9;
    int t2 = t & 511;                  // 512 tiles/expert: 16 (I) x 32 (H)
    int cx = t2 & 31;
    int ry = t2 >> 5;
    int r0 = ry * 32, c0 = cx * 32;    // r over I=512, c over H=1024
    const float* src = w4 + (size_t)e * 512 * 1024;
    uint16_t* dst = w4b + (size_t)e * 1024 * 512;
    int tx = tid & 31;
    int ty = tid >> 5;
#pragma unroll
    for (int j = 0; j < 32; j += 8)
        tile[ty + j][tx] = src[(size_t)(r0 + ty + j) * 1024 + (c0 + tx)];
    __syncthreads();
#pragma unroll
    for (int j = 0; j < 32; j += 8)
        dst[(size_t)(c0 + ty + j) * 512 + (r0 + tx)] = f32_to_bf16_rne(tile[tx][ty + j]);
}

__device__ __forceinline__ void storeC4(float* p, float4 v) { *(float4*)p = v; }
__device__ __forceinline__ void storeC4(uint16_t* p, float4 v) {
    ushort4v u;
    u[0] = f32_to_bf16_rne(v.x); u[1] = f32_to_bf16_rne(v.y);
    u[2] = f32_to_bf16_rne(v.z); u[3] = f32_to_bf16_rne(v.w);
    *(ushort4v*)p = u;
}

// C[e][M][N] = A[e][M][K] * B[e][N][K]^T, B bf16 K-contiguous, A bf16 or fp32.
// Tile BMv x BNv, BK=64, WM x WN waves, each wave AF x BF MFMA 16x16x32 frags.
// bf16-A: counted-vmcnt ping-pong (round-4 verified): barrier; stage(next);
//   vmcnt(8) [= old tile's loads]; barrier; compute. Never vmcnt(0) in loop.
// fp32-A: syncthreads ping-pong, A reg-staged: issue A loads + B lds-loads for
//   t+1, compute(t) [hides A latency], then cvt+ds_write A(t+1).
// LDS slot swizzle kb' = kb ^ (row&7) keeps fragment ds_read_b128 conflict-free.
// Epilogue bounces acc through LDS for coalesced dwordx4 C stores.
template <int WM, int WN, int AF, int BF, bool SWZ, int GXS, typename AT, typename OutT>
__global__ __launch_bounds__(WM * WN * 64, 2) void gemm_tn(
    const AT* __restrict__ A,
    const uint16_t* __restrict__ B,
    OutT* __restrict__ C,
    int M, int N, int K)
{
    constexpr int BK = 64;
    constexpr int BMv = WM * AF * 16;
    constexpr int BNv = WN * BF * 16;
    constexpr int THREADS = WM * WN * 64;
    constexpr int ROWS = THREADS / 8;    // tile rows staged per instruction set
    constexpr int AI = BMv / ROWS;       // A stage iterations (=4 in both configs)
    constexpr int BI = BNv / ROWS;       // B stage iterations (=4)
    constexpr bool A32 = sizeof(AT) == 4;

    __shared__ __align__(16) uint16_t As[2][BMv * BK];
    __shared__ __align__(16) uint16_t Bs[2][BNv * BK];

    const int tid  = threadIdx.x;
    const int lane = tid & 63;
    const int wave = tid >> 6;
    const int wr = wave / WN, wc = wave % WN;
    const int frow = lane & 15;
    const int quad = lane >> 4;
    const int xm = frow & 7;

    int bxi, byi, e;
    if constexpr (SWZ) {
        // XCD-chunked bijective swizzle (gridDim.x divisible by 8)
        int chunk = gridDim.x >> 3;
        int id2 = (blockIdx.x & 7) * chunk + (blockIdx.x >> 3);
        bxi = id2 & ((1 << GXS) - 1);
        int rest = id2 >> GXS;
        byi = rest & 15;               // gy = 4096/256 = 16 (main GEMM only)
        e = rest >> 4;
    } else {
        bxi = blockIdx.x; byi = blockIdx.y; e = blockIdx.z;
    }
    const int bm = byi * BMv;
    const int bn = bxi * BNv;

    // staging map: thread t covers LDS 16B slot (row = t>>3 + ROWS*i, slot = t&7);
    // global source k-block kb = (t&7) ^ (row&7)
    const int srow = tid >> 3;
    const int skb  = (tid & 7) ^ (srow & 7);
    const AT* Ag = A + (size_t)e * M * K + (size_t)(bm + srow) * K + skb * 8;
    const uint16_t* Bg = B + (size_t)e * N * K + (size_t)(bn + srow) * K + skb * 8;

    float4v acc[AF][BF];
#pragma unroll
    for (int i = 0; i < AF; ++i)
#pragma unroll
        for (int j = 0; j < BF; ++j)
            acc[i][j] = (float4v){0.f, 0.f, 0.f, 0.f};

    const int ldsuni = wave * 1024;    // wave-uniform part of tid*16

    auto stageB = [&](int buf, int k0) {
        char* bsb = (char*)Bs + buf * (BNv * BK * 2);
#pragma unroll
        for (int i = 0; i < BI; ++i) {
            __builtin_amdgcn_global_load_lds(
                (const __attribute__((address_space(1))) void*)(Bg + k0 + (size_t)i * ROWS * K),
                (__attribute__((address_space(3))) void*)(bsb + i * (ROWS * 128) + ldsuni),
                16, 0, 0);
        }
    };

    auto compute = [&](int buf) {
        const char* asb = (const char*)As + buf * (BMv * BK * 2);
        const char* bsb = (const char*)Bs + buf * (BNv * BK * 2);
#pragma unroll
        for (int s = 0; s < 2; ++s) {
            short8 a[AF], b[BF];
            const int kb = ((s * 4 + quad) ^ xm) * 16;
#pragma unroll
            for (int f = 0; f < AF; ++f)
                a[f] = *(const short8*)(asb + (wr * (AF * 16) + f * 16 + frow) * 128 + kb);
#pragma unroll
            for (int f = 0; f < BF; ++f)
                b[f] = *(const short8*)(bsb + (wc * (BF * 16) + f * 16 + frow) * 128 + kb);
#pragma unroll
            for (int i = 0; i < AF; ++i)
#pragma unroll
                for (int j = 0; j < BF; ++j)
                    acc[i][j] = __builtin_amdgcn_mfma_f32_16x16x32_bf16(a[i], b[j], acc[i][j], 0, 0, 0);
        }
    };

    const int nk = K / BK;
    int cur = 0;

    if constexpr (!A32) {
        auto stageA = [&](int buf, int k0) {
            char* asb = (char*)As + buf * (BMv * BK * 2);
#pragma unroll
            for (int i = 0; i < AI; ++i) {
                __builtin_amdgcn_global_load_lds(
                    (const __attribute__((address_space(1))) void*)((const uint16_t*)Ag + k0 + (size_t)i * ROWS * K),
                    (__attribute__((address_space(3))) void*)(asb + i * (ROWS * 128) + ldsuni),
                    16, 0, 0);
            }
        };
        stageA(0, 0); stageB(0, 0);          // 8 loads in flight
        for (int t = 0; t + 1 < nk; ++t) {
            __builtin_amdgcn_s_barrier();    // (a) readers of buf[cur^1] done; no drain
            __builtin_amdgcn_sched_barrier(0);
            stageA(cur ^ 1, (t + 1) * BK);
            stageB(cur ^ 1, (t + 1) * BK);   // -> 16 outstanding
            asm volatile("s_waitcnt vmcnt(8)" ::: "memory");  // old 8 (buf[cur]) landed
            __builtin_amdgcn_s_barrier();    // (b) everyone's buf[cur] ready
            __builtin_amdgcn_sched_barrier(0);
            compute(cur);
            cur ^= 1;
        }
        asm volatile("s_waitcnt vmcnt(0)" ::: "memory");
        __builtin_amdgcn_s_barrier();
        __builtin_amdgcn_sched_barrier(0);
        compute(cur);
    } else {
        float4 av0[AI], av1[AI];
        auto issueA = [&](int k0) {
#pragma unroll
            for (int i = 0; i < AI; ++i) {
                const float* src = (const float*)Ag + k0 + (size_t)i * ROWS * K;
                av0[i] = *(const float4*)(src);
                av1[i] = *(const float4*)(src + 4);
            }
        };
        auto writeA = [&](int buf) {
            char* asb = (char*)As + buf * (BMv * BK * 2);
#pragma unroll
            for (int i = 0; i < AI; ++i) {
                short8 s;
                s[0] = (short)f32_to_bf16_rne(av0[i].x);
                s[1] = (short)f32_to_bf16_rne(av0[i].y);
                s[2] = (short)f32_to_bf16_rne(av0[i].z);
                s[3] = (short)f32_to_bf16_rne(av0[i].w);
                s[4] = (short)f32_to_bf16_rne(av1[i].x);
                s[5] = (short)f32_to_bf16_rne(av1[i].y);
                s[6] = (short)f32_to_bf16_rne(av1[i].z);
                s[7] = (short)f32_to_bf16_rne(av1[i].w);
                *(short8*)(asb + i * (ROWS * 128) + tid * 16) = s;
            }
        };
        issueA(0); stageB(0, 0); writeA(0);
        for (int t = 0; t < nk; ++t) {
            __syncthreads();                 // publishes buf[cur] (A ds_writes + B lds-loads)
            if (t + 1 < nk) { issueA((t + 1) * BK); stageB(cur ^ 1, (t + 1) * BK); }
            compute(cur);                    // A-load latency hides under MFMAs
            if (t + 1 < nk) writeA(cur ^ 1);
            cur ^= 1;
        }
    }

    // ---- epilogue: LDS bounce (per-wave 16x64 f32 region, row stride 68)
    __syncthreads();
    float* bounce = (float*)((char*)As + wave * 4352);
    OutT* Ce = C + (size_t)e * M * N;
    const int colbase = bn + wc * (BF * 16);
#pragma unroll
    for (int f = 0; f < AF; ++f) {
#pragma unroll
        for (int j = 0; j < BF; ++j)
#pragma unroll
            for (int r = 0; r < 4; ++r)
                bounce[(quad * 4 + r) * 68 + j * 16 + frow] = acc[f][j][r];
        int row0 = bm + wr * (AF * 16) + f * 16;
#pragma unroll
        for (int p = 0; p < 4; ++p) {
            int lrow = p * 4 + (lane >> 4);
            int lcol = (lane & 15) * 4;
            float4 v = *(const float4*)(bounce + lrow * 68 + lcol);
            storeC4(&Ce[(size_t)(row0 + lrow) * N + colbase + lcol], v);
        }
    }
}

extern "C" void kernel_launch(void* const* d_in, const int* in_sizes, int n_in,
                              void* d_out, int out_size, void* d_ws, size_t ws_size,
                              hipStream_t stream) {
    const float* x  = (const float*)d_in[0];
    const float* w1 = (const float*)d_in[1];
    const float* w2 = (const float*)d_in[2];
    const float* w3 = (const float*)d_in[3];
    const float* w4 = (const float*)d_in[4];
    float* out = (float*)d_out;

    const int E = 8, T = 4096, H = 1024, I = 512;

    char* p = (char*)d_ws;
    uint16_t* w1c = (uint16_t*)p; p += (size_t)E * H * I * 2;       // 8 MiB  [E][H][I]
    uint16_t* w2c = (uint16_t*)p; p += (size_t)E * H * I * 2;       // 8 MiB  [E][I][H]
    uint16_t* w3c = (uint16_t*)p; p += (size_t)E * H * I * 2;       // 8 MiB  [E][H][I]
    uint16_t* w4b = (uint16_t*)p; p += (size_t)E * H * I * 2;       // 8 MiB  [E][H][I] (w4^T)
    float*    Q1  = (float*)p;    p += (size_t)E * H * H * 4;       // 32 MiB [E][H][H]
    float*    Q2  = (float*)p;    p += (size_t)E * H * I * 4;       // 16 MiB [E][H][I]
    uint16_t* Wt  = (uint16_t*)p; p += (size_t)E * H * H * 2;       // 16 MiB [E][H][H]
    // total 96 MiB

    prep<<<dim3(3072 + 4096), dim3(256), 0, stream>>>(w1, w2, w3, w4, w1c, w2c, w3c, w4b);

    // Q1 = w4^T @ w3^T   [1024x512]x[512x1024]
    gemm_tn<2, 2, 4, 4, false, 0, uint16_t, float>
        <<<dim3(8, 8, 8), dim3(256), 0, stream>>>(w4b, w3c, Q1, H, H, I);
    // Q2 = Q1 @ w2^T     [1024x1024]x[1024x512]
    gemm_tn<2, 2, 4, 4, false, 0, float, float>
        <<<dim3(4, 8, 8), dim3(256), 0, stream>>>(Q1, w2c, Q2, H, I, H);
    // Wt = Q2 @ w1^T     [1024x512]x[512x1024]
    gemm_tn<2, 2, 4, 4, false, 0, float, uint16_t>
        <<<dim3(8, 8, 8), dim3(256), 0, stream>>>(Q2, w1c, Wt, H, H, I);
    // out = x @ Wt^T     [4096x1024]x[1024x1024] per expert, fp32 in/out
    gemm_tn<2, 4, 8, 4, true, 2, float, float>
        <<<dim3((H / 256) * (T / 256) * E), dim3(512), 0, stream>>>(x, Wt, out, T, H, H);
}